// Round 10
// baseline (173.465 us; speedup 1.0000x reference)
//
#include <hip/hip_runtime.h>

// GaussianRecuModel: B=512 batches, T=8192-step affine recurrence on 2-state x.
//   x_{t+1} = Mt x_t + bt,  Mt = I + dt*A - dt*(xic_t C),  bt = xic_t dy_t
//   out_t   = dt * C x_t   (state BEFORE update)
//
// R4:    wave-coalesced float4 global access; XOR-swizzled LDS transposes.
// R5-R10: 1024-thr monolith dead end (1 block/CU, 64-VGPR hard cap; every
//        register-pipeline attempt spilled, WRITE_SIZE 32->97 MB).
// R11/R12: 512-thr blocks, 2 chunks/batch, LDS carry. Still spilled (~13
//        regs): base body peaks ~52 (a[32]+d[16] live through replay) and
//        chunk state pushed past the 64 cap.
// R13:   shrink the body's register working set. d[] and o4[] move into a
//        per-wave 4 KiB "dyout" LDS slice with owner-XOR swizzle
//        X(o)=(o>>1)&3 -- all four access phases (coalesced dy write,
//        per-pair own read, per-pair out write-in-place, coalesced out read)
//        hit all 8 bank-groups per 8-lane group. Replay overwrites each dy
//        slot with its out pair (slot-local, same thread). Frees 32 regs:
//        body peak ~50 < 64 even with chunk-loop state. a[] stays in regs.

#define B_   512
#define T_   8192
#define LPT  8                   // steps per thread per chunk
#define NT   512                 // threads per block (8 waves)
#define NW   (NT / 64)           // waves per block
#define NCH  2                   // chunks per batch
static_assert(NT * LPT * NCH == T_, "chunks cover one batch");

#define SLICE_F4 128             // 2 KiB work slice per wave (xic + headers)
#define DYO_F4   256             // 4 KiB dyout slice per wave

struct Aff { float m00, m01, m10, m11, v0, v1; };

__device__ __forceinline__ Aff aff_compose(const Aff& L, const Aff& E) {
    Aff r;
    r.m00 = L.m00*E.m00 + L.m01*E.m10;
    r.m01 = L.m00*E.m01 + L.m01*E.m11;
    r.m10 = L.m10*E.m00 + L.m11*E.m10;
    r.m11 = L.m10*E.m01 + L.m11*E.m11;
    r.v0  = L.m00*E.v0  + L.m01*E.v1 + L.v0;
    r.v1  = L.m10*E.v0  + L.m11*E.v1 + L.v1;
    return r;
}

__device__ __forceinline__ Aff aff_identity() {
    Aff r; r.m00 = 1.f; r.m01 = 0.f; r.m10 = 0.f; r.m11 = 1.f; r.v0 = 0.f; r.v1 = 0.f;
    return r;
}

// Step map with explicit dy components (no d[] array).
// Uses a[] and the cd/i constants of the enclosing scope.
#define STEPM(i, S, dyx, dyy)                                           \
    {                                                                   \
        const float4 x4 = a[i];                                         \
        (S).m00 = i00 - (x4.x*cd00 + x4.y*cd10);                        \
        (S).m01 = i01 - (x4.x*cd01 + x4.y*cd11);                        \
        (S).m10 = i10 - (x4.z*cd00 + x4.w*cd10);                        \
        (S).m11 = i11 - (x4.z*cd01 + x4.w*cd11);                        \
        (S).v0  = x4.x*(dyx) + x4.y*(dyy);                              \
        (S).v1  = x4.z*(dyx) + x4.w*(dyy);                              \
    }

__global__ __launch_bounds__(NT, 4) void grm_fused(
    const float* __restrict__ xic, const float* __restrict__ dy,
    const float* __restrict__ Aptr, const float* __restrict__ Cptr,
    float4* __restrict__ out4)
{
    // work : 8 waves x 2 KiB (xic transpose rounds + scan headers)
    // dyout: 8 waves x 4 KiB (dy in, out in place), owner-XOR swizzled
    // carry: 1 float4 slot (chunk-state handoff, barrier-separated)
    __shared__ float4 lds4[NW * SLICE_F4 + NW * DYO_F4 + 1];
    float4* workb = lds4;
    float4* dyob  = lds4 + NW * SLICE_F4;
    float*  carry = (float*)(lds4 + NW * SLICE_F4 + NW * DYO_F4);

    const int b    = blockIdx.x;
    const int tid  = threadIdx.x;
    const int lane = tid & 63;
    const int wave = tid >> 6;

    float4* slice  = workb + wave * SLICE_F4;
    float4* dslice = dyob  + wave * DYO_F4;

    const float DT = 1e-3f;
    const float cd00 = Cptr[0]*DT, cd01 = Cptr[1]*DT;
    const float cd10 = Cptr[2]*DT, cd11 = Cptr[3]*DT;
    const float i00 = 1.0f + Aptr[0]*DT, i01 = Aptr[1]*DT;
    const float i10 = Aptr[2]*DT,        i11 = 1.0f + Aptr[3]*DT;

    // initial state x = [1, 0]; first read is after chunk-0's first barrier
    if (tid == 0) { carry[0] = 1.0f; carry[1] = 0.0f; }

    #pragma unroll 1
    for (int c = 0; c < NCH; ++c) {
        // global bases in float4 units; wave covers 512 steps of this chunk
        const int wbase = b * T_ + c * (NT * LPT) + wave * 512;
        const float4* xw = (const float4*)xic + wbase;          // 512 f4
        const float4* dw = (const float4*)dy  + (wbase >> 1);   // 256 f4
        float4*       ow = out4 + (wbase >> 1);                 // 256 f4

        // ---- issue this chunk's global loads, fully coalesced ----
        float4 t[8], u[4];
        #pragma unroll
        for (int j = 0; j < 8; ++j) t[j] = xw[j*64 + lane];
        #pragma unroll
        for (int j = 0; j < 4; ++j) u[j] = dw[j*64 + lane];

        // ---- xic transpose: four owner-rounds through the 2 KiB slice ----
        // Round r covers f in [128r,128r+128); owner o=f>>3, rel=o&15,
        // slot=lane&7, swizzled addr = rel*8 + (slot^(rel&7)). Writes
        // conflict-free; reads 2-way max (free). Same-wave DS ordering
        // makes cross-round slice reuse safe without barriers.
        float4 a[LPT];
        #pragma unroll
        for (int r = 0; r < 4; ++r) {
            #pragma unroll
            for (int jj = 0; jj < 2; ++jj) {
                int j = 2*r + jj;
                int f = j*64 + lane;
                int rel = (f >> 3) & 15;
                slice[rel*8 + ((lane & 7) ^ (rel & 7))] = t[j];
            }
            if ((lane >> 4) == r) {
                int rel = lane & 15;
                #pragma unroll
                for (int s = 0; s < LPT; ++s)
                    a[s] = slice[rel*8 + (s ^ (rel & 7))];
            }
        }

        // ---- dy deposit: coalesced u[] -> swizzled dyout slice (once) ----
        // f = j*64+lane; owner o = f>>2; addr = o*4 + ((f&3) ^ ((o>>1)&3)).
        // Each 8-lane group covers all 8 bank-groups (X(o)=(o>>1)&3 chosen
        // so (lane&1, X) is bijective over lane mod 8).
        #pragma unroll
        for (int j = 0; j < 4; ++j) {
            int o = j*16 + (lane >> 2);
            dslice[o*4 + ((lane & 3) ^ ((o >> 1) & 3))] = u[j];
        }

        // ---- thread-local compose: P = T7 o ... o T0 ----
        // dy pair k lives at own addr lane*4 + (k ^ ((lane>>1)&3)).
        Aff P;
        #pragma unroll
        for (int k = 0; k < 4; ++k) {
            const float4 dk = dslice[lane*4 + (k ^ ((lane >> 1) & 3))];
            Aff s;
            STEPM(2*k, s, dk.x, dk.y);
            if (k == 0) P = s; else P = aff_compose(s, P);
            STEPM(2*k + 1, s, dk.z, dk.w);
            P = aff_compose(s, P);
        }

        // ---- wave Kogge-Stone inclusive scan (64 lanes) ----
        Aff S = P;
        #pragma unroll
        for (int sh = 1; sh < 64; sh <<= 1) {
            Aff q;
            q.m00 = __shfl_up(S.m00, sh); q.m01 = __shfl_up(S.m01, sh);
            q.m10 = __shfl_up(S.m10, sh); q.m11 = __shfl_up(S.m11, sh);
            q.v0  = __shfl_up(S.v0,  sh); q.v1  = __shfl_up(S.v1,  sh);
            if (lane >= sh) S = aff_compose(S, q);
        }

        // ---- wave totals -> own slice header (slice free: a in regs) ----
        if (lane == 63) {
            float* h = (float*)slice;
            h[0] = S.m00; h[1] = S.m01; h[2] = S.m10; h[3] = S.m11;
            h[4] = S.v0;  h[5] = S.v1;
        }
        __syncthreads();                       // B1

        // chunk-entering state (uniform; written last chunk or at init)
        const float xc0 = carry[0], xc1 = carry[1];

        // ---- wave-exclusive prefix (runtime loop, Ew only) ----
        Aff Ew = aff_identity();
        for (int w = 0; w < wave; ++w) {
            const float* h = (const float*)(workb + w * SLICE_F4);
            Aff t2;
            t2.m00 = h[0]; t2.m01 = h[1]; t2.m10 = h[2]; t2.m11 = h[3];
            t2.v0  = h[4]; t2.v1  = h[5];
            Ew = aff_compose(t2, Ew);
        }
        __syncthreads();                       // B2: headers consumed

        // ---- lane-exclusive prefix within wave ----
        Aff El;
        El.m00 = __shfl_up(S.m00, 1); El.m01 = __shfl_up(S.m01, 1);
        El.m10 = __shfl_up(S.m10, 1); El.m11 = __shfl_up(S.m11, 1);
        El.v0  = __shfl_up(S.v0,  1); El.v1  = __shfl_up(S.v1,  1);
        if (lane == 0) El = aff_identity();

        Aff E = aff_compose(El, Ew);
        // thread's entering state = E applied to the chunk-entering state
        float x0 = E.m00*xc0 + E.m01*xc1 + E.v0;
        float x1 = E.m10*xc0 + E.m11*xc1 + E.v1;

        // ---- replay: read dy pair, emit out pair IN PLACE (same slot) ----
        #pragma unroll
        for (int k = 0; k < 4; ++k) {
            const int ad = lane*4 + (k ^ ((lane >> 1) & 3));
            const float4 dk = dslice[ad];
            float4 op;
            op.x = cd00*x0 + cd01*x1;
            op.y = cd10*x0 + cd11*x1;
            {
                Aff s; STEPM(2*k, s, dk.x, dk.y);
                float nx0 = s.m00*x0 + s.m01*x1 + s.v0;
                float nx1 = s.m10*x0 + s.m11*x1 + s.v1;
                x0 = nx0; x1 = nx1;
            }
            op.z = cd00*x0 + cd01*x1;
            op.w = cd10*x0 + cd11*x1;
            {
                Aff s; STEPM(2*k + 1, s, dk.z, dk.w);
                float nx0 = s.m00*x0 + s.m01*x1 + s.v0;
                float nx1 = s.m10*x0 + s.m11*x1 + s.v1;
                x0 = nx0; x1 = nx1;
            }
            dslice[ad] = op;   // dy slot becomes out slot (thread-local)
        }

        // ---- last thread holds the chunk-final state: publish carry.
        // Write after B2 of this chunk; reads after B1 of next -> race-free.
        if (wave == NW-1 && lane == 63) { carry[0] = x0; carry[1] = x1; }

        // ---- coalesced out store straight from the swizzled slice ----
        #pragma unroll
        for (int j = 0; j < 4; ++j) {
            int f = j*64 + lane;
            int o = f >> 2;
            ow[f] = dslice[o*4 + ((lane & 3) ^ ((o >> 1) & 3))];
        }
        // next chunk's deposits rewrite this wave's own slices -- same-wave
        // DS ordering after the reads above makes that safe.
    }
}

#undef STEPM

extern "C" void kernel_launch(void* const* d_in, const int* in_sizes, int n_in,
                              void* d_out, int out_size, void* d_ws, size_t ws_size,
                              hipStream_t stream) {
    const float* xic  = (const float*)d_in[0];   // [B,T,2,2]
    const float* dy   = (const float*)d_in[1];   // [B,T,2]
    const float* Aptr = (const float*)d_in[2];   // [2,2]
    const float* Cptr = (const float*)d_in[3];   // [2,2]
    float4* out = (float4*)d_out;                // [B,T,2]

    grm_fused<<<B_, NT, 0, stream>>>(xic, dy, Aptr, Cptr, out);
}